// Round 4
// baseline (466.303 us; speedup 1.0000x reference)
//
#include <hip/hip_runtime.h>
#include <math.h>

#define NPTS  50000
#define NSP   4000
#define NW    4              // waves per 64-point group
#define KNN   11
#define BIG   3.4e38f
#define BCAP  224            // per-wave pass-B admitted-list capacity
#define SPH   65536u         // spoint-hist key base (points use [0,65536))
#define NKEY  131072

#define MED3(a,b,c) __builtin_amdgcn_fmed3f((a),(b),(c))

// Static scratch: shared hist (points morton | spoints linear), sorted copies.
__device__ unsigned g_hist[NKEY];
__device__ float4   g_sorted[2 * NPTS];   // points  (x,y,z, orig_idx_bits)
__device__ float4   g_sp[2 * NSP];        // spoints (x,y,z, orig_idx_bits), cell-sorted

static __device__ __forceinline__ unsigned spread5(unsigned v) {
    return (v & 1u) | ((v & 2u) << 2) | ((v & 4u) << 4) |
           ((v & 8u) << 6) | ((v & 16u) << 8);
}
static __device__ __forceinline__ int cellc(float v) {      // [-4,4) -> [0,32)
    return min(max((int)floorf(fmaf(v, 4.0f, 16.0f)), 0), 31);
}
static __device__ __forceinline__ unsigned pkey(int b, float x, float y, float z) {
    const int gx = cellc(x), gy = cellc(y), gz = cellc(z);  // points: morton
    return ((unsigned)b << 15) | spread5((unsigned)gx) |
           (spread5((unsigned)gy) << 1) | (spread5((unsigned)gz) << 2);
}
static __device__ __forceinline__ unsigned skey(int b, float x, float y, float z) {
    const int gx = cellc(x), gy = cellc(y), gz = cellc(z);  // spoints: linear, x fastest
    return SPH + ((unsigned)b << 15) + (unsigned)(gx + (gy << 5) + (gz << 10));
}
static __device__ __forceinline__ float rflf(float v) {
    return __int_as_float(__builtin_amdgcn_readfirstlane(__float_as_int(v)));
}
static __device__ __forceinline__ int rfli(int v) {
    return __builtin_amdgcn_readfirstlane(v);
}
static __device__ __forceinline__ float wred_min(float v) {
#pragma unroll
    for (int off = 32; off > 0; off >>= 1) v = fminf(v, __shfl_xor(v, off, 64));
    return v;
}
static __device__ __forceinline__ float wred_max(float v) {
#pragma unroll
    for (int off = 32; off > 0; off >>= 1) v = fmaxf(v, __shfl_xor(v, off, 64));
    return v;
}

__global__ void k_zero() {
    g_hist[blockIdx.x * 256 + threadIdx.x] = 0u;       // grid exactly NKEY/256
}

__global__ void k_hist(const float* __restrict__ pts, const float* __restrict__ spts) {
    const int n = blockIdx.x * 256 + threadIdx.x;
    if (n < 2 * NPTS) {
        const float* p = pts + (size_t)n * 3;
        atomicAdd(&g_hist[pkey(n >= NPTS, p[0], p[1], p[2])], 1u);
    } else if (n < 2 * NPTS + 2 * NSP) {
        const int m = n - 2 * NPTS;
        const float* p = spts + (size_t)m * 3;
        atomicAdd(&g_hist[skey(m >= NSP, p[0], p[1], p[2])], 1u);
    }
}

// 4 blocks: {pts b0, pts b1, spts b0, spts b1}; exclusive scan of 32768 keys each.
__global__ void k_scan() {
    __shared__ unsigned part[1024];
    const int t = threadIdx.x;
    const unsigned base = (unsigned)blockIdx.x * 32768u + (unsigned)t * 32u;
    unsigned s = 0;
#pragma unroll
    for (int j = 0; j < 32; ++j) s += g_hist[base + j];
    part[t] = s;
    __syncthreads();
    for (int off = 1; off < 1024; off <<= 1) {
        unsigned v = (t >= off) ? part[t - off] : 0u;
        __syncthreads();
        part[t] += v;
        __syncthreads();
    }
    const unsigned rb = (blockIdx.x == 1) ? NPTS : (blockIdx.x == 3) ? NSP : 0u;
    unsigned run = rb + part[t] - s;
#pragma unroll
    for (int j = 0; j < 32; ++j) {
        const unsigned h = g_hist[base + j];
        g_hist[base + j] = run;        // start offsets; scatter turns them into ends
        run += h;
    }
}

__global__ void k_scatter(const float* __restrict__ pts, const float* __restrict__ spts) {
    const int n = blockIdx.x * 256 + threadIdx.x;
    if (n < 2 * NPTS) {
        const float* p = pts + (size_t)n * 3;
        const int b = (n >= NPTS);
        const float x = p[0], y = p[1], z = p[2];
        const unsigned dst = atomicAdd(&g_hist[pkey(b, x, y, z)], 1u);
        g_sorted[dst] = make_float4(x, y, z, __uint_as_float((unsigned)(n - b * NPTS)));
    } else if (n < 2 * NPTS + 2 * NSP) {
        const int m = n - 2 * NPTS;
        const float* p = spts + (size_t)m * 3;
        const int b = (m >= NSP);
        const float x = p[0], y = p[1], z = p[2];
        const unsigned dst = atomicAdd(&g_hist[skey(b, x, y, z)], 1u);
        g_sp[dst] = make_float4(x, y, z, __uint_as_float((unsigned)(m - b * NSP)));
    }
}

// Block = 4 waves x one 64-point Morton group. Spoints are cell-sorted (linear key,
// x fastest), so for each (gy,gz) row the admissible gx-interval [cells with
// boxdist(cell,groupbox) <= Trad] is closed-form AND contiguous in the sorted array:
// 2 scalar range loads per row, no per-cell or per-candidate filtering. Rows are
// round-robin across the 4 waves; exact med3 top-11 chain + union merge; pass B
// replays the ballot-admitted LDS list (provable superset of every nd<=d10g set).
// Conservative bound: d(s,p) >= boxdist(cell(s)_ext, groupbox); d11(p) <= D_ub + R.
__global__ __launch_bounds__(256, 4) void voronoi_kernel(
    const float* __restrict__ spts,   // (2, NSP, 3) original
    float* __restrict__ out)          // (2, NPTS)
{
    __shared__ float  lds_d[NW][64][13];   // merge lists (stride 13 coprime 32)
    __shared__ int    lds_i[NW][64];
    __shared__ float  lds_b[NW][64];
    __shared__ float4 sl[NW][BCAP];        // pass-B admitted lists

    const int b    = blockIdx.y;
    const int lane = threadIdx.x & 63;
    const int wq   = threadIdx.x >> 6;     // wave id (wave-uniform)
    int pi = blockIdx.x * 64 + lane;
    const bool valid = (pi < NPTS);
    if (!valid) pi = NPTS - 1;             // clamp; lanes stay active

    const float4 P = g_sorted[(size_t)b * NPTS + pi];
    const float px = P.x, py = P.y, pz = P.z;
    const unsigned orig = __float_as_uint(P.w);

    // ---- group bbox + radius, forced to SGPR (scalar cell math + s_load streams) ----
    const float mnx = rflf(wred_min(px)), mxx = rflf(wred_max(px));
    const float mny = rflf(wred_min(py)), mxy = rflf(wred_max(py));
    const float mnz = rflf(wred_min(pz)), mxz = rflf(wred_max(pz));
    const float ccx = 0.5f * (mnx + mxx);
    const float ccy = 0.5f * (mny + mxy);
    const float ccz = 0.5f * (mnz + mxz);
    const float R = rflf(sqrtf(wred_max(
        fmaf(px - ccx, px - ccx, fmaf(py - ccy, py - ccy, (pz - ccz) * (pz - ccz))))));

    const unsigned bb = (unsigned)b * NSP;
    const unsigned hb = SPH + ((unsigned)b << 15);

    // ---- D_ub: expanding-region lane-parallel scan + 11-extract ----
    // Lane-mins are over disjoint candidate subsets => 11th extract is a valid upper
    // bound on d11(cc)^2 whenever >=11 candidates were seen; else region doubles.
    float m11 = BIG;
    float h = 0.4f;
    for (int it = 0; it < 8; ++it) {
        const int xa = rfli(cellc(ccx - h)), xb = rfli(cellc(ccx + h));
        const int ya = rfli(cellc(ccy - h)), yb = rfli(cellc(ccy + h));
        const int za = rfli(cellc(ccz - h)), zb = rfli(cellc(ccz + h));
        float vv = BIG;
        unsigned off = 0;
        for (int gz = za; gz <= zb; ++gz)
            for (int gy = ya; gy <= yb; ++gy) {
                const int lx0 = xa + (gy << 5) + (gz << 10);
                const unsigned e0 = lx0 ? g_hist[hb + lx0 - 1] : bb;
                const unsigned e1 = g_hist[hb + lx0 + (xb - xa)];
                const unsigned w = e1 - e0;
                for (unsigned s = (unsigned)((lane + 64 - (int)(off & 63u)) & 63);
                     s < w; s += 64) {                    // lane-rotated: spreads rows
                    const float4 c = g_sp[e0 + s];
                    const float dx = c.x - ccx, dy = c.y - ccy, dz = c.z - ccz;
                    vv = fminf(vv, fmaf(dx, dx, fmaf(dy, dy, dz * dz)));
                }
                off += w;
            }
        float m = BIG;
#pragma unroll
        for (int t = 0; t < KNN; ++t) { m = wred_min(vv); vv = (vv == m) ? BIG : vv; }
        if (m < 1e37f) { m11 = m; break; }
        h *= 2.0f;
    }
    const float Trad = fminf(sqrtf(m11) + R, 64.0f);     // cap -> fallback stays exact
    const float Tc = rflf(fmaf(Trad * Trad, 1.0004f, 1e-12f));  // fp-safety margin
    const float TradU = rflf(Trad);

    const int gy0 = rfli(cellc(mny - TradU)), gy1 = rfli(cellc(mxy + TradU));
    const int gz0 = rfli(cellc(mnz - TradU)), gz1 = rfli(cellc(mxz + TradU));
    const bool fb = ((gy1 - gy0 + 1) * (gz1 - gz0 + 1) > 512);   // tail fallback

    // Row enumeration: border cells get +/-inf extents (clamped outliers stay valid).
    auto forEachRow = [&](auto&& stream) {
        int t = 0;
        for (int gz = gz0; gz <= gz1; ++gz) {
            const float czl = (gz == 0)  ? -1e30f : fmaf((float)gz, 0.25f, -4.0f);
            const float czh = (gz == 31) ?  1e30f : fmaf((float)gz, 0.25f, -3.75f);
            const float gzp = fmaxf(fmaxf(mnz - czh, czl - mxz), 0.0f);
            const float z2 = gzp * gzp;
            if (z2 > Tc) { t += (gy1 - gy0 + 1); continue; }
            for (int gy = gy0; gy <= gy1; ++gy, ++t) {
                if ((t & 3) != wq) continue;               // round-robin rows
                const float cyl = (gy == 0)  ? -1e30f : fmaf((float)gy, 0.25f, -4.0f);
                const float cyh = (gy == 31) ?  1e30f : fmaf((float)gy, 0.25f, -3.75f);
                const float gyp = fmaxf(fmaxf(mny - cyh, cyl - mxy), 0.0f);
                const float b2 = fmaf(gyp, gyp, z2);
                if (b2 > Tc) continue;
                const float rr = sqrtf(Tc - b2);           // closed-form gx interval
                const int xai = cellc(mnx - rr);
                const int xbi = cellc(mxx + rr);
                const int lx0 = xai + (gy << 5) + (gz << 10);
                const unsigned e0 = lx0 ? g_hist[hb + lx0 - 1] : bb;
                const unsigned e1 = g_hist[hb + lx0 + (xbi - xai)];
                stream(e0, e1);                            // ONE contiguous range
            }
        }
    };

    // ---- pass A: exact top-11 med3 chain over scalar-loaded candidate stream ----
    float d0 = BIG, d1 = BIG, d2 = BIG, d3 = BIG, d4 = BIG, d5 = BIG,
          d6 = BIG, d7 = BIG, d8 = BIG, d9 = BIG, d10 = BIG;
    int i0 = 0x7fffffff;
    unsigned bcnt = 0;

    auto streamA = [&](unsigned beg, unsigned end) {
        if (beg >= end) return;
        float4 cur = g_sp[beg];
        for (unsigned t = beg; t < end; ++t) {
            const unsigned tn = (t + 1 < end) ? (t + 1) : t;
            const float4 nxt = g_sp[tn];                   // 1-deep prefetch
            const float dx = px - cur.x, dy = py - cur.y, dz = pz - cur.z;
            const float nd = fmaf(dx, dx, fmaf(dy, dy, dz * dz));
            if (__ballot(nd < d10)) {
                if (lane == 0 && bcnt < BCAP) sl[wq][bcnt] = cur;  // admitted list
                ++bcnt;
                const int jj = (int)__float_as_uint(cur.w);
                d10 = MED3(d9, d10, nd);
                d9  = MED3(d8, d9,  nd);
                d8  = MED3(d7, d8,  nd);
                d7  = MED3(d6, d7,  nd);
                d6  = MED3(d5, d6,  nd);
                d5  = MED3(d4, d5,  nd);
                d4  = MED3(d3, d4,  nd);
                d3  = MED3(d2, d3,  nd);
                d2  = MED3(d1, d2,  nd);
                d1  = MED3(d0, d1,  nd);
                i0  = (nd < d0) ? jj : ((nd == d0 && jj < i0) ? jj : i0);  // lex ties
                d0  = fminf(d0, nd);
            }
            cur = nxt;
        }
    };

    if (!fb) forEachRow(streamA);
    else streamA(bb + (unsigned)wq * (NSP / NW), bb + (unsigned)(wq + 1) * (NSP / NW));

    // ---- publish + exact union merge across the 4 waves (verified round-0 code) ----
    lds_d[wq][lane][0]  = d0;  lds_d[wq][lane][1]  = d1;
    lds_d[wq][lane][2]  = d2;  lds_d[wq][lane][3]  = d3;
    lds_d[wq][lane][4]  = d4;  lds_d[wq][lane][5]  = d5;
    lds_d[wq][lane][6]  = d6;  lds_d[wq][lane][7]  = d7;
    lds_d[wq][lane][8]  = d8;  lds_d[wq][lane][9]  = d9;
    lds_d[wq][lane][10] = d10;
    lds_i[wq][lane] = i0;
    __syncthreads();

    float gb = BIG; int gi = 0x7fffffff;
#pragma unroll
    for (int q = 0; q < NW; ++q) {
        const float dq = lds_d[q][lane][0];
        const int   iq = lds_i[q][lane];
        const bool take = (dq < gb) || (dq == gb && iq < gi);
        gb = take ? dq : gb;
        gi = take ? iq : gi;
    }
#define INS(v) { \
        d10 = MED3(d9, d10, (v)); \
        d9  = MED3(d8, d9,  (v)); \
        d8  = MED3(d7, d8,  (v)); \
        d7  = MED3(d6, d7,  (v)); \
        d6  = MED3(d5, d6,  (v)); \
        d5  = MED3(d4, d5,  (v)); \
        d4  = MED3(d3, d4,  (v)); \
        d3  = MED3(d2, d3,  (v)); \
        d2  = MED3(d1, d2,  (v)); \
        d1  = MED3(d0, d1,  (v)); \
        d0  = fminf(d0, (v)); }
#pragma unroll
    for (int q = 0; q < NW; ++q) {
        if (q == wq) continue;
#pragma unroll
        for (int k = 0; k < 11; ++k) INS(lds_d[q][lane][k]);
    }
    const float d10g = d10;                 // exact union 11th-smallest
    const int   i0g  = gi;                  // exact lexicographic argmin

    // ---- pass B: edge distance; replay admitted list (superset of nd<=d10g) ----
    const float* ip = spts + (size_t)b * NSP * 3 + (size_t)(unsigned)i0g * 3;
    const float ix = ip[0], iy = ip[1], iz = ip[2];
    const float vx = px - ix, vy = py - iy, vz = pz - iz;
    float best = BIG;

    auto candB = [&](const float4 c) {
        const float dx = px - c.x, dy = py - c.y, dz = pz - c.z;
        const float nd = fmaf(dx, dx, fmaf(dy, dy, dz * dz));
        const int jj = (int)__float_as_uint(c.w);
        const bool adm = (nd <= d10g) && (jj != i0g);
        if (__ballot(adm)) {
            const float ex = c.x - ix, ey = c.y - iy, ez = c.z - iz;
            const float ee = fmaf(ex, ex, fmaf(ey, ey, ez * ez));
            const float dt = fmaf(vx, ex, fmaf(vy, ey, vz * ez));
            const float u  = fmaf(-0.5f, ee, dt);
            const float t2 = u * u * __builtin_amdgcn_rcpf(ee);
            best = adm ? fminf(best, t2) : best;   // NaN (ee=0) masked by adm
        }
    };
    auto streamB = [&](unsigned beg, unsigned end) {
        if (beg >= end) return;
        float4 cur = g_sp[beg];
        for (unsigned t = beg; t < end; ++t) {
            const unsigned tn = (t + 1 < end) ? (t + 1) : t;
            const float4 nxt = g_sp[tn];
            candB(cur);
            cur = nxt;
        }
    };

    if (bcnt <= BCAP) {                     // common: tiny LDS replay
        if (bcnt) {
            float4 cur = sl[wq][0];
            for (unsigned k = 0; k < bcnt; ++k) {
                const unsigned kn = (k + 1 < bcnt) ? (k + 1) : k;
                const float4 nxt = sl[wq][kn];
                candB(cur);
                cur = nxt;
            }
        }
    } else if (!fb) {
        forEachRow(streamB);                // rare overflow: restream rows
    } else {
        streamB(bb + (unsigned)wq * (NSP / NW), bb + (unsigned)(wq + 1) * (NSP / NW));
    }

    // ---- final min across the 4 waves ----
    lds_b[wq][lane] = best;
    __syncthreads();
    if (wq == 0) {
        const float m = fminf(fminf(lds_b[0][lane], lds_b[1][lane]),
                              fminf(lds_b[2][lane], lds_b[3][lane]));
        if (valid) out[(size_t)b * NPTS + orig] = m;
    }
}

extern "C" void kernel_launch(void* const* d_in, const int* in_sizes, int n_in,
                              void* d_out, int out_size, void* d_ws, size_t ws_size,
                              hipStream_t stream) {
    (void)in_sizes; (void)n_in; (void)d_ws; (void)ws_size; (void)out_size;
    const float* pts  = (const float*)d_in[0];   // (2, 50000, 3)
    const float* spts = (const float*)d_in[1];   // (2, 4000, 3)
    float* out = (float*)d_out;                  // (2, 50000)

    const int nht = 2 * NPTS + 2 * NSP;          // hist/scatter thread count
    k_zero   <<<dim3(NKEY / 256),          dim3(256),  0, stream>>>();
    k_hist   <<<dim3((nht + 255) / 256),   dim3(256),  0, stream>>>(pts, spts);
    k_scan   <<<dim3(4),                   dim3(1024), 0, stream>>>();
    k_scatter<<<dim3((nht + 255) / 256),   dim3(256),  0, stream>>>(pts, spts);
    voronoi_kernel<<<dim3((NPTS + 63) / 64, 2), dim3(256), 0, stream>>>(spts, out);
}

// Round 5
// 258.287 us; speedup vs baseline: 1.8054x; 1.8054x over previous
//
#include <hip/hip_runtime.h>
#include <math.h>

#define NPTS  50000
#define NSP   4000
#define NGRP  1000           // NSP/4 candidate quads
#define NW    8              // waves per 64-point group
#define QW    (NGRP / NW)    // 125 quads per wave
#define KNN   11
#define BIG   3.4e38f
#define SEGCAP 128           // per-wave shortlist capacity (flush granularity 64)
#define SEGPAD 8
#define SEGSTR (SEGCAP + SEGPAD)
#define GRIDC 32
#define NKEY  65536          // 2 batches * 32^3 cells (points only)

#define MED3(a,b,c) __builtin_amdgcn_fmed3f((a),(b),(c))

// Static scratch: counting-sort hist/offsets + sorted points.
__device__ unsigned g_hist[NKEY];
__device__ float4   g_sorted[2 * NPTS];   // (x,y,z, orig_idx_bits)

static __device__ __forceinline__ unsigned spread5(unsigned v) {
    return (v & 1u) | ((v & 2u) << 2) | ((v & 4u) << 4) |
           ((v & 8u) << 6) | ((v & 16u) << 8);
}

static __device__ __forceinline__ unsigned cell_key(int b, float x, float y, float z) {
    int gx = (int)floorf((x + 4.0f) * 4.0f);
    int gy = (int)floorf((y + 4.0f) * 4.0f);
    int gz = (int)floorf((z + 4.0f) * 4.0f);
    gx = min(max(gx, 0), GRIDC - 1);
    gy = min(max(gy, 0), GRIDC - 1);
    gz = min(max(gz, 0), GRIDC - 1);
    unsigned m = spread5((unsigned)gx) | (spread5((unsigned)gy) << 1) |
                 (spread5((unsigned)gz) << 2);
    return ((unsigned)b << 15) | m;
}

__global__ void k_zero() {
    int t = blockIdx.x * 256 + threadIdx.x;
    if (t < NKEY) g_hist[t] = 0u;
}

__global__ void k_hist(const float* __restrict__ pts) {
    int n = blockIdx.x * 256 + threadIdx.x;
    if (n >= 2 * NPTS) return;
    const float* p = pts + (size_t)n * 3;
    int b = (n >= NPTS) ? 1 : 0;
    atomicAdd(&g_hist[cell_key(b, p[0], p[1], p[2])], 1u);
}

__global__ void k_scan() {
    __shared__ unsigned part[1024];
    const int t = threadIdx.x;
    const unsigned base = (unsigned)blockIdx.x * 32768u + (unsigned)t * 32u;
    unsigned s = 0;
#pragma unroll
    for (int j = 0; j < 32; ++j) s += g_hist[base + j];
    part[t] = s;
    __syncthreads();
    for (int off = 1; off < 1024; off <<= 1) {
        unsigned v = (t >= off) ? part[t - off] : 0u;
        __syncthreads();
        part[t] += v;
        __syncthreads();
    }
    unsigned run = (unsigned)blockIdx.x * (unsigned)NPTS + part[t] - s;
#pragma unroll
    for (int j = 0; j < 32; ++j) {
        unsigned h = g_hist[base + j];
        g_hist[base + j] = run;
        run += h;
    }
}

__global__ void k_scatter(const float* __restrict__ pts) {
    int n = blockIdx.x * 256 + threadIdx.x;
    if (n >= 2 * NPTS) return;
    const float* p = pts + (size_t)n * 3;
    int b = (n >= NPTS) ? 1 : 0;
    float x = p[0], y = p[1], z = p[2];
    unsigned dst = atomicAdd(&g_hist[cell_key(b, x, y, z)], 1u);
    if (dst < 2u * NPTS)
        g_sorted[dst] = make_float4(x, y, z, __uint_as_float((unsigned)(n - b * NPTS)));
}

static __device__ __forceinline__ float wred_min(float v) {
#pragma unroll
    for (int off = 32; off > 0; off >>= 1) v = fminf(v, __shfl_xor(v, off, 64));
    return v;
}
static __device__ __forceinline__ float wred_max(float v) {
#pragma unroll
    for (int off = 32; off > 0; off >>= 1) v = fmaxf(v, __shfl_xor(v, off, 64));
    return v;
}

// Block = 8 waves x one 64-point Morton group. Each wave filters its EIGHTH of the
// candidates (original index order -> lex argmin within wave is automatic) through the
// conservative group-box test into its own LDS segment; flush-resume chunking bounds
// overflow cost by the admissible count (no brute fallback). Exact med3 top-11 chain
// per wave, exact union merge across the 8 waves (sorted lists -> ballot early-break),
// pass B replays the box-admitted list (provable superset of every nd<=d10g set).
//   p in group, s in top-11(p)  =>  boxdist(s,groupbox) <= d11(c) + R <= sqrt(m11) + R.
__global__ __launch_bounds__(512, 6) void voronoi_kernel(
    const float* __restrict__ spts,   // (2, NSP, 3)
    float* __restrict__ out)          // (2, NPTS)
{
    __shared__ float4 sl[NW * SEGSTR];     // 17.4 KiB shortlist segments
    __shared__ float  lds_d[NW][64][13];   // 26.6 KiB merge lists (stride 13 coprime 32)
    __shared__ int    lds_i[NW][64];
    __shared__ float  lds_b[NW][64];
    __shared__ float  lds_m[NW];

    const int b    = blockIdx.y;
    const int lane = threadIdx.x & 63;
    const int wq   = threadIdx.x >> 6;     // wave id = candidate eighth (wave-uniform)
    int pi = blockIdx.x * 64 + lane;
    const bool valid = (pi < NPTS);
    if (!valid) pi = NPTS - 1;             // clamp; lanes stay active

    const float4 P = g_sorted[(size_t)b * NPTS + pi];
    const float px = P.x, py = P.y, pz = P.z;
    const unsigned orig = __float_as_uint(P.w);

    // ---- group bbox + radius (identical in all waves; exact regardless of sort) ----
    const float mnx = wred_min(px), mxx = wred_max(px);
    const float mny = wred_min(py), mxy = wred_max(py);
    const float mnz = wred_min(pz), mxz = wred_max(pz);
    const float ccx = 0.5f * (mnx + mxx);
    const float ccy = 0.5f * (mny + mxy);
    const float ccz = 0.5f * (mnz + mxz);
    const float R = sqrtf(wred_max(
        fmaf(px - ccx, px - ccx, fmaf(py - ccy, py - ccy, (pz - ccz) * (pz - ccz)))));

    const float4* __restrict__ spq = (const float4*)(spts + (size_t)b * NSP * 3);
    const int g0 = wq * QW, g1 = g0 + QW;

    // ---- D_ub: per-lane min over disjoint subsets of OWN eighth, 11 extract-mins.
    // 11th-extract over the 64 disjoint lane-mins is >= 11 distinct candidate dists
    //   => valid upper bound on d11(c)^2; min over the 8 waves stays valid.
    float myMin = BIG;
    for (int k0 = g0; k0 < g1; k0 += 64) {
        const int g  = k0 + lane;
        const int gc = (g < g1) ? g : (g1 - 1);
        const float4 q0 = spq[3 * gc + 0];
        const float4 q1 = spq[3 * gc + 1];
        const float4 q2 = spq[3 * gc + 2];
        float dx = q0.x - ccx, dy = q0.y - ccy, dz = q0.z - ccz;
        float md = fmaf(dx, dx, fmaf(dy, dy, dz * dz));
        dx = q0.w - ccx; dy = q1.x - ccy; dz = q1.y - ccz;
        md = fminf(md, fmaf(dx, dx, fmaf(dy, dy, dz * dz)));
        dx = q1.z - ccx; dy = q1.w - ccy; dz = q2.x - ccz;
        md = fminf(md, fmaf(dx, dx, fmaf(dy, dy, dz * dz)));
        dx = q2.y - ccx; dy = q2.z - ccy; dz = q2.w - ccz;
        md = fminf(md, fmaf(dx, dx, fmaf(dy, dy, dz * dz)));
        if (g < g1) myMin = fminf(myMin, md);
    }
    float vv = myMin, m11 = 0.0f;
#pragma unroll
    for (int t = 0; t < KNN; ++t) {
        m11 = wred_min(vv);
        vv = (vv == m11) ? BIG : vv;       // extra tie-removal only loosens (still valid)
    }
    if (lane == 0) lds_m[wq] = m11;
    __syncthreads();
    float m11g = BIG;
#pragma unroll
    for (int q = 0; q < NW; ++q) m11g = fminf(m11g, lds_m[q]);
    const float Trad = sqrtf(m11g) + R;
    const float T = Trad * Trad * 1.0004f + 1e-12f;   // fp-safety margin

#define ADM(sx, sy, sz) \
    (fmaf(MED3((sx), mnx, mxx) - (sx), MED3((sx), mnx, mxx) - (sx), \
     fmaf(MED3((sy), mny, mxy) - (sy), MED3((sy), mny, mxy) - (sy), \
          (MED3((sz), mnz, mxz) - (sz)) * (MED3((sz), mnz, mxz) - (sz)))) <= T)

    const int segbase = wq * SEGSTR;
    unsigned cnt = 0;

    auto padseg = [&]() {                  // 8 sentinels cover round-up + prefetch
        if (lane < SEGPAD)
            sl[segbase + (int)cnt + lane] =
                make_float4(1e18f, 1e18f, 1e18f, __uint_as_float(0x7fffffffu));
    };

    // Flush-resume build: before each PUSH (<=64 new entries) ensure room; flush =
    // pad + consume + reset. No candidate is ever dropped; overflow cost ~ admissible
    // count. consume(cnt) is also called once at the end.
#define PUSH(sx, sy, sz, ok, idx, CONSUME) { \
        if (cnt > (unsigned)(SEGCAP - 64)) {                /* wave-uniform */ \
            padseg(); CONSUME(cnt); cnt = 0; of = true; \
        } \
        const unsigned long long msk = __ballot(ok); \
        if (ok) { \
            const unsigned pos = cnt + \
                __builtin_amdgcn_mbcnt_hi((unsigned)(msk >> 32), \
                    __builtin_amdgcn_mbcnt_lo((unsigned)msk, 0u)); \
            sl[segbase + (int)pos] = \
                make_float4((sx), (sy), (sz), __uint_as_float((unsigned)(idx))); \
        } \
        cnt += (unsigned)__popcll(msk); }

#define RUN_BUILD(CONSUME, ofvar) { \
        ofvar = false; bool& of = ofvar; cnt = 0; \
        for (int k0 = g0; k0 < g1; k0 += 64) { \
            const int g  = k0 + lane; \
            const int gc = (g < g1) ? g : (g1 - 1); \
            const bool in = (g < g1); \
            const float4 q0 = spq[3 * gc + 0]; \
            const float4 q1 = spq[3 * gc + 1]; \
            const float4 q2 = spq[3 * gc + 2]; \
            const bool a0 = in && ADM(q0.x, q0.y, q0.z); \
            const bool a1 = in && ADM(q0.w, q1.x, q1.y); \
            const bool a2 = in && ADM(q1.z, q1.w, q2.x); \
            const bool a3 = in && ADM(q2.y, q2.z, q2.w); \
            PUSH(q0.x, q0.y, q0.z, a0, 4 * gc + 0, CONSUME); \
            PUSH(q0.w, q1.x, q1.y, a1, 4 * gc + 1, CONSUME); \
            PUSH(q1.z, q1.w, q2.x, a2, 4 * gc + 2, CONSUME); \
            PUSH(q2.y, q2.z, q2.w, a3, 4 * gc + 3, CONSUME); \
        } \
        padseg(); CONSUME(cnt); }

    // ---- pass A: exact top-11 med3 chain over shortlist chunks ----
    float d0 = BIG, d1 = BIG, d2 = BIG, d3 = BIG, d4 = BIG, d5 = BIG,
          d6 = BIG, d7 = BIG, d8 = BIG, d9 = BIG, d10 = BIG;
    int i0 = 0x7fffffff;

#define CHAIN(nd, jj) { \
        if (__ballot((nd) < d10)) { \
            d10 = MED3(d9, d10, (nd)); \
            d9  = MED3(d8, d9,  (nd)); \
            d8  = MED3(d7, d8,  (nd)); \
            d7  = MED3(d6, d7,  (nd)); \
            d6  = MED3(d5, d6,  (nd)); \
            d5  = MED3(d4, d5,  (nd)); \
            d4  = MED3(d3, d4,  (nd)); \
            d3  = MED3(d2, d3,  (nd)); \
            d2  = MED3(d1, d2,  (nd)); \
            d1  = MED3(d0, d1,  (nd)); \
            i0  = ((nd) < d0) ? (jj) : i0; \
            d0  = fminf(d0, (nd)); \
        } }
#define CANDA(c) { \
        const float dx = px - (c).x, dy = py - (c).y, dz = pz - (c).z; \
        const float nd = fmaf(dx, dx, fmaf(dy, dy, dz * dz)); \
        const int jj = (int)__float_as_uint((c).w); \
        CHAIN(nd, jj); }

    auto chainA = [&](unsigned n) {
        if (n == 0u) return;
        float4 e0 = sl[segbase + 0], e1 = sl[segbase + 1],
               e2 = sl[segbase + 2], e3 = sl[segbase + 3];
        for (unsigned k = 0; k < n; k += 4) {            // 4-deep ds_read pipeline
            const float4 n0 = sl[segbase + (int)k + 4];
            const float4 n1 = sl[segbase + (int)k + 5];
            const float4 n2 = sl[segbase + (int)k + 6];
            const float4 n3 = sl[segbase + (int)k + 7];
            CANDA(e0); CANDA(e1); CANDA(e2); CANDA(e3);
            e0 = n0; e1 = n1; e2 = n2; e3 = n3;
        }
    };

    bool ovfA;
    RUN_BUILD(chainA, ovfA);
    const unsigned cntA = cnt;             // intact shortlist size iff !ovfA

    // ---- publish + exact union merge across the 8 waves ----
    lds_d[wq][lane][0]  = d0;  lds_d[wq][lane][1]  = d1;
    lds_d[wq][lane][2]  = d2;  lds_d[wq][lane][3]  = d3;
    lds_d[wq][lane][4]  = d4;  lds_d[wq][lane][5]  = d5;
    lds_d[wq][lane][6]  = d6;  lds_d[wq][lane][7]  = d7;
    lds_d[wq][lane][8]  = d8;  lds_d[wq][lane][9]  = d9;
    lds_d[wq][lane][10] = d10;
    lds_i[wq][lane] = i0;
    __syncthreads();

    float gb = BIG; int gi = 0x7fffffff;
#pragma unroll
    for (int q = 0; q < NW; ++q) {
        const float dq = lds_d[q][lane][0];
        const int   iq = lds_i[q][lane];
        const bool take = (dq < gb) || (dq == gb && iq < gi);
        gb = take ? dq : gb;
        gi = take ? iq : gi;
    }
#define INS(v) { \
        d10 = MED3(d9, d10, (v)); \
        d9  = MED3(d8, d9,  (v)); \
        d8  = MED3(d7, d8,  (v)); \
        d7  = MED3(d6, d7,  (v)); \
        d6  = MED3(d5, d6,  (v)); \
        d5  = MED3(d4, d5,  (v)); \
        d4  = MED3(d3, d4,  (v)); \
        d3  = MED3(d2, d3,  (v)); \
        d2  = MED3(d1, d2,  (v)); \
        d1  = MED3(d0, d1,  (v)); \
        d0  = fminf(d0, (v)); }
    // Foreign lists are sorted ascending: once no lane has v < d10, the rest of that
    // list (and its tail) is a provable no-op -> ballot early-break.
#pragma unroll
    for (int q = 0; q < NW; ++q) {
        if (q == wq) continue;
#pragma unroll
        for (int k = 0; k < 11; ++k) {
            const float v = lds_d[q][lane][k];
            if (!__ballot(v < d10)) break;
            INS(v);
        }
    }
    const float d10g = d10;                // exact union 11th-smallest
    const int   i0g  = gi;                 // exact lexicographic argmin

    // ---- pass B: edge distance over the admissible set ----
    const float* ip = spts + (size_t)b * NSP * 3 + (size_t)(unsigned)i0g * 3;
    const float ix = ip[0], iy = ip[1], iz = ip[2];
    const float vx = px - ix, vy = py - iy, vz = pz - iz;
    float best = BIG;

#define CANDB(c) { \
        const float dx = px - (c).x, dy = py - (c).y, dz = pz - (c).z; \
        const float nd = fmaf(dx, dx, fmaf(dy, dy, dz * dz)); \
        const int jj = (int)__float_as_uint((c).w); \
        const bool adm = (nd <= d10g) && (jj != i0g); \
        if (__ballot(adm)) { \
            const float ex = (c).x - ix, ey = (c).y - iy, ez = (c).z - iz; \
            const float ee = fmaf(ex, ex, fmaf(ey, ey, ez * ez)); \
            const float dt = fmaf(vx, ex, fmaf(vy, ey, vz * ez)); \
            const float u  = fmaf(-0.5f, ee, dt); \
            const float t2 = u * u * __builtin_amdgcn_rcpf(ee); \
            best = adm ? fminf(best, t2) : best; \
        } }

    auto scanB = [&](unsigned n) {
        if (n == 0u) return;
        float4 e0 = sl[segbase + 0], e1 = sl[segbase + 1],
               e2 = sl[segbase + 2], e3 = sl[segbase + 3];
        for (unsigned k = 0; k < n; k += 4) {
            const float4 n0 = sl[segbase + (int)k + 4];
            const float4 n1 = sl[segbase + (int)k + 5];
            const float4 n2 = sl[segbase + (int)k + 6];
            const float4 n3 = sl[segbase + (int)k + 7];
            CANDB(e0); CANDB(e1); CANDB(e2); CANDB(e3);
            e0 = n0; e1 = n1; e2 = n2; e3 = n3;
        }
    };

    if (!ovfA) {
        scanB(cntA);                       // reuse intact shortlist
    } else {
        bool ovfB;
        RUN_BUILD(scanB, ovfB);            // rare: rebuild with flush-resume (exact)
        (void)ovfB;
    }

    // ---- final min across the 8 waves ----
    lds_b[wq][lane] = best;
    __syncthreads();
    if (wq == 0) {
        float m = lds_b[0][lane];
#pragma unroll
        for (int q = 1; q < NW; ++q) m = fminf(m, lds_b[q][lane]);
        if (valid) out[(size_t)b * NPTS + orig] = m;
    }
}

extern "C" void kernel_launch(void* const* d_in, const int* in_sizes, int n_in,
                              void* d_out, int out_size, void* d_ws, size_t ws_size,
                              hipStream_t stream) {
    (void)in_sizes; (void)n_in; (void)d_ws; (void)ws_size; (void)out_size;
    const float* pts  = (const float*)d_in[0];   // (2, 50000, 3)
    const float* spts = (const float*)d_in[1];   // (2, 4000, 3)
    float* out = (float*)d_out;                  // (2, 50000)

    k_zero   <<<dim3(NKEY / 256),            dim3(256),  0, stream>>>();
    k_hist   <<<dim3((2 * NPTS + 255)/256),  dim3(256),  0, stream>>>(pts);
    k_scan   <<<dim3(2),                     dim3(1024), 0, stream>>>();
    k_scatter<<<dim3((2 * NPTS + 255)/256),  dim3(256),  0, stream>>>(pts);
    voronoi_kernel<<<dim3((NPTS + 63)/64, 2), dim3(512), 0, stream>>>(spts, out);
}